// Round 6
// baseline (884.952 us; speedup 1.0000x reference)
//
#include <hip/hip_runtime.h>
#include <hip/hip_bf16.h>

// MultiHeadImageAttentionBlock on MI355X.
// Pipeline: wcast -> im2col -> conv(q,k,v) GEMMs -> Z (softmax-over-q denom)
//        -> attn write (single pass, 512MB, the HBM floor) + PV fused
//        -> im2col(x) -> conv(o) split-K -> +bias+2*residual + LN stats -> LN.

typedef __attribute__((ext_vector_type(4))) float f32x4;
typedef __attribute__((ext_vector_type(8))) short short8;
typedef __attribute__((ext_vector_type(8))) unsigned short ushort8;
typedef unsigned short u16;

__device__ __forceinline__ u16 f2bu(float f) {
    unsigned u = __float_as_uint(f);
    u += 0x7fffu + ((u >> 16) & 1u);   // RNE
    return (u16)(u >> 16);
}

// ---------------- kernel 1: weight casts (fold 1/sqrt(32) into wq/bq) ----------------
__global__ __launch_bounds__(256) void k_wcast(
    const float* __restrict__ wq, const float* __restrict__ wk,
    const float* __restrict__ wv, const float* __restrict__ wo,
    const float* __restrict__ bq,
    u16* wqb, u16* wkb, u16* wvb, u16* wob, float* bqs) {
    int i = blockIdx.x * 256 + threadIdx.x;
    const float s = 0.17677669529663687f; // 1/sqrt(32)
    if (i < 147456) {
        wqb[i] = f2bu(wq[i] * s);
        wkb[i] = f2bu(wk[i]);
        wvb[i] = f2bu(wv[i]);
        wob[i] = f2bu(wo[i]);
    }
    if (i < 256) bqs[i] = bq[i] * s;
}

// ---------------- kernel 2: im2col of query(4) + seq(16) images -> bf16 ----------------
// rows 0..4095: query b*1024+p ; rows 4096..20479: seq img(n*4+b)*1024+p. k = cin*9+tap.
__global__ __launch_bounds__(256) void k_imcol1(const float* __restrict__ qimg,
                                                const float* __restrict__ seq,
                                                u16* __restrict__ imcol) {
    int id = blockIdx.x * 256 + threadIdx.x; // 20480*64
    int row = id >> 6, cin = id & 63;
    const float* base;
    if (row < 4096) base = qimg + ((size_t)(row >> 10) * 64 + cin) * 1024;
    else            base = seq + ((size_t)((row - 4096) >> 10) * 64 + cin) * 1024;
    int pix = row & 1023, py = pix >> 5, px = pix & 31;
    u16* o = imcol + (size_t)row * 576 + cin * 9;
#pragma unroll
    for (int ky = 0; ky < 3; ky++)
#pragma unroll
        for (int kx = 0; kx < 3; kx++) {
            int y = py + ky - 1, x = px + kx - 1;
            float v = (y >= 0 && y < 32 && x >= 0 && x < 32) ? base[y * 32 + x] : 0.f;
            o[ky * 3 + kx] = f2bu(v);
        }
}

// ---------------- kernel 3: generic conv-GEMM: C[M rows][och] = A(im2col) @ W^T ----------------
// wg tile 128x64, 4 waves (2x2), wave tile 64x32, K step 32 (one 16x16x32 MFMA per tile).
// mode 0=q 1=k 2=v (bf16 out, different layouts), 3=o (f32 split-K partials).
__global__ __launch_bounds__(256) void k_conv(
    const u16* __restrict__ A, int ldA,
    const u16* __restrict__ Wb, int ldW,
    const float* __restrict__ bias, int mode,
    u16* __restrict__ ob16, float* __restrict__ of32) {
    __shared__ u16 As[128][40];  // +8 pad: 2-way-free bank pattern on ds_read_b128
    __shared__ u16 Bs[64][40];
    int t = threadIdx.x, l = t & 63, w = t >> 6;
    int m0 = blockIdx.x * 128, n0 = blockIdx.y * 64;
    int kbeg = blockIdx.z * 576;
    int wm = (w >> 1) * 64, wn = (w & 1) * 32;
    f32x4 acc[4][2] = {};
    for (int k0 = 0; k0 < 576; k0 += 32) {
        __syncthreads();
        {
            int row = t >> 1, sg = (t & 1) * 16;
            const u16* as = A + (size_t)(m0 + row) * ldA + kbeg + k0 + sg;
            *(ushort8*)&As[row][sg] = *(const ushort8*)as;
            *(ushort8*)&As[row][sg + 8] = *(const ushort8*)(as + 8);
            int r2 = t >> 2, sg2 = (t & 3) * 8;
            const u16* bs = Wb + (size_t)(n0 + r2) * ldW + kbeg + k0 + sg2;
            *(ushort8*)&Bs[r2][sg2] = *(const ushort8*)bs;
        }
        __syncthreads();
        short8 bf0 = *(const short8*)&Bs[wn + (l & 15)][(l >> 4) * 8];
        short8 bf1 = *(const short8*)&Bs[wn + 16 + (l & 15)][(l >> 4) * 8];
#pragma unroll
        for (int mt = 0; mt < 4; mt++) {
            short8 af = *(const short8*)&As[wm + mt * 16 + (l & 15)][(l >> 4) * 8];
            acc[mt][0] = __builtin_amdgcn_mfma_f32_16x16x32_bf16(af, bf0, acc[mt][0], 0, 0, 0);
            acc[mt][1] = __builtin_amdgcn_mfma_f32_16x16x32_bf16(af, bf1, acc[mt][1], 0, 0, 0);
        }
    }
    // epilogue; C layout: col = l&15, row = (l>>4)*4 + r  [m89-verified]
#pragma unroll
    for (int mt = 0; mt < 4; mt++)
#pragma unroll
        for (int nt = 0; nt < 2; nt++) {
            int och = n0 + wn + nt * 16 + (l & 15);
            float bi = (mode == 3) ? 0.f : bias[och];
#pragma unroll
            for (int r = 0; r < 4; r++) {
                int row = m0 + wm + mt * 16 + (l >> 4) * 4 + r;
                float v = acc[mt][nt][r] + bi;
                if (mode == 0) {        // qb[b][h][p][d]
                    int b = row >> 10, p = row & 1023, h = och >> 5, d = och & 31;
                    ob16[((size_t)(b * 8 + h) * 1024 + p) * 32 + d] = f2bu(v);
                } else if (mode == 1) { // kb[b][h][n*1024+p][d]
                    int img = row >> 10, p = row & 1023, n = img >> 2, b = img & 3;
                    int h = och >> 5, d = och & 31;
                    ob16[((size_t)(b * 8 + h) * 4096 + n * 1024 + p) * 32 + d] = f2bu(v);
                } else if (mode == 2) { // vb[b][h][d][n*1024+p]
                    int img = row >> 10, p = row & 1023, n = img >> 2, b = img & 3;
                    int h = och >> 5, d = och & 31;
                    ob16[((size_t)(b * 8 + h) * 32 + d) * 4096 + n * 1024 + p] = f2bu(v);
                } else {                // P4[z][row][och]
                    of32[((size_t)blockIdx.z * 4096 + row) * 64 + och] = v;
                }
            }
        }
}

// ---------------- kernel 4: invZ[b][h][k] = 1 / sum_q exp(s[q,k]) ----------------
// grid (32 bh, 16 ktiles of 256). Wave w owns 64 key cols; loops 8 q-chunks of 128.
__global__ __launch_bounds__(256) void k_z(const u16* __restrict__ qb,
                                           const u16* __restrict__ kb,
                                           float* __restrict__ invZ) {
    __shared__ u16 Ks[256][40];
    __shared__ u16 Qs[128][40];
    int t = threadIdx.x, l = t & 63, w = t >> 6;
    int bh = blockIdx.x, kt = blockIdx.y;
    {
        const u16* src = kb + ((size_t)bh * 4096 + kt * 256 + t) * 32;
#pragma unroll
        for (int s = 0; s < 4; s++) *(ushort8*)&Ks[t][s * 8] = *(const ushort8*)(src + s * 8);
    }
    __syncthreads();
    short8 bf[4];
#pragma unroll
    for (int nt = 0; nt < 4; nt++)
        bf[nt] = *(const short8*)&Ks[w * 64 + nt * 16 + (l & 15)][(l >> 4) * 8];
    float za[4] = {0.f, 0.f, 0.f, 0.f};
    for (int qc = 0; qc < 8; qc++) {
        __syncthreads();
        {
            int row = t >> 1, sg = (t & 1) * 16;
            const u16* src = qb + ((size_t)bh * 1024 + qc * 128 + row) * 32 + sg;
            *(ushort8*)&Qs[row][sg] = *(const ushort8*)src;
            *(ushort8*)&Qs[row][sg + 8] = *(const ushort8*)(src + 8);
        }
        __syncthreads();
#pragma unroll
        for (int mt = 0; mt < 8; mt++) {
            short8 af = *(const short8*)&Qs[mt * 16 + (l & 15)][(l >> 4) * 8];
#pragma unroll
            for (int nt = 0; nt < 4; nt++) {
                f32x4 z4 = {0.f, 0.f, 0.f, 0.f};
                f32x4 s4 = __builtin_amdgcn_mfma_f32_16x16x32_bf16(af, bf[nt], z4, 0, 0, 0);
                za[nt] += __expf(s4[0]) + __expf(s4[1]) + __expf(s4[2]) + __expf(s4[3]);
            }
        }
    }
#pragma unroll
    for (int nt = 0; nt < 4; nt++) {
        float z = za[nt];
        z += __shfl_xor(z, 16);
        z += __shfl_xor(z, 32);
        if (l < 16) invZ[(size_t)bh * 4096 + kt * 256 + w * 64 + nt * 16 + l] = 1.f / z;
    }
}

// ---------------- kernel 5: attn write (single pass) + PV fused ----------------
// grid (32 bh, 16 qchunks of 64). Wave w owns 16 q rows. K looped in chunks of 128.
__global__ __launch_bounds__(256) void k_attn(
    const u16* __restrict__ qb, const u16* __restrict__ kb, const u16* __restrict__ vb,
    const float* __restrict__ invZ, float* __restrict__ attn, float* __restrict__ xb) {
    __shared__ u16 Qs[64][40];
    __shared__ u16 Ks[128][40];
    __shared__ u16 Vs[32][136];
    __shared__ u16 Ps[4][16][136];   // per-wave normalized-P staging for PV A-operand
    int t = threadIdx.x, l = t & 63, w = t >> 6;
    int bh = blockIdx.x, qc = blockIdx.y;
    int b = bh >> 3, h = bh & 7;
    {
        int row = t >> 2, sg = (t & 3) * 8;
        *(ushort8*)&Qs[row][sg] =
            *(const ushort8*)(qb + ((size_t)bh * 1024 + qc * 64 + row) * 32 + sg);
    }
    __syncthreads();
    short8 qf = *(const short8*)&Qs[w * 16 + (l & 15)][(l >> 4) * 8];
    f32x4 xacc[2] = {};
    const int qrow0 = qc * 64 + w * 16 + (l >> 4) * 4;
    for (int kc = 0; kc < 32; kc++) {
        __syncthreads();  // previous iteration's LDS reads complete
        {
            int row = t >> 1, sg = (t & 1) * 16;
            const u16* src = kb + ((size_t)bh * 4096 + kc * 128 + row) * 32 + sg;
            *(ushort8*)&Ks[row][sg] = *(const ushort8*)src;
            *(ushort8*)&Ks[row][sg + 8] = *(const ushort8*)(src + 8);
            int d = t >> 3, s = t & 7;
            const u16* vsrc = vb + ((size_t)bh * 32 + d) * 4096 + kc * 128 + s * 16;
            *(ushort8*)&Vs[d][s * 16] = *(const ushort8*)vsrc;
            *(ushort8*)&Vs[d][s * 16 + 8] = *(const ushort8*)(vsrc + 8);
        }
        __syncthreads();
#pragma unroll
        for (int nt = 0; nt < 8; nt++) {
            short8 kf = *(const short8*)&Ks[nt * 16 + (l & 15)][(l >> 4) * 8];
            f32x4 z4 = {0.f, 0.f, 0.f, 0.f};
            f32x4 s4 = __builtin_amdgcn_mfma_f32_16x16x32_bf16(qf, kf, z4, 0, 0, 0);
            float iz = invZ[(size_t)bh * 4096 + kc * 128 + nt * 16 + (l & 15)];
            float* ab = attn + ((size_t)bh * 1024 + qrow0) * 4096 + kc * 128 + nt * 16 + (l & 15);
#pragma unroll
            for (int r = 0; r < 4; r++) {
                float e = __expf(s4[r]) * iz;
                ab[(size_t)r * 4096] = e;
                Ps[w][(l >> 4) * 4 + r][nt * 16 + (l & 15)] = f2bu(e);
            }
        }
        __syncthreads();  // P visible; then PV
#pragma unroll
        for (int dt = 0; dt < 2; dt++)
#pragma unroll
            for (int ks = 0; ks < 4; ks++) {
                short8 pf = *(const short8*)&Ps[w][l & 15][ks * 32 + (l >> 4) * 8];
                short8 vf = *(const short8*)&Vs[dt * 16 + (l & 15)][ks * 32 + (l >> 4) * 8];
                xacc[dt] = __builtin_amdgcn_mfma_f32_16x16x32_bf16(pf, vf, xacc[dt], 0, 0, 0);
            }
    }
    // x[b][och=h*32+d][qpix], f32
#pragma unroll
    for (int dt = 0; dt < 2; dt++)
#pragma unroll
        for (int r = 0; r < 4; r++)
            xb[((size_t)b * 256 + h * 32 + dt * 16 + (l & 15)) * 1024 +
               qc * 64 + w * 16 + (l >> 4) * 4 + r] = xacc[dt][r];
}

// ---------------- kernel 6: im2col of x for output conv ----------------
__global__ __launch_bounds__(256) void k_imcol2(const float* __restrict__ xb,
                                                u16* __restrict__ xcol) {
    int id = blockIdx.x * 256 + threadIdx.x; // 4096*256
    int row = id >> 8, cin = id & 255;
    int b = row >> 10, pix = row & 1023, py = pix >> 5, px = pix & 31;
    const float* base = xb + ((size_t)b * 256 + cin) * 1024;
    u16* o = xcol + (size_t)row * 2304 + cin * 9;
#pragma unroll
    for (int ky = 0; ky < 3; ky++)
#pragma unroll
        for (int kx = 0; kx < 3; kx++) {
            int y = py + ky - 1, x = px + kx - 1;
            float v = (y >= 0 && y < 32 && x >= 0 && x < 32) ? base[y * 32 + x] : 0.f;
            o[ky * 3 + kx] = f2bu(v);
        }
}

// ---------------- kernel 7: sum split-K partials + bias + 2*residual; LN stats ----------------
__global__ __launch_bounds__(256) void k_post1(const float* __restrict__ P4,
                                               const float* __restrict__ bo,
                                               const float* __restrict__ qimg,
                                               float* __restrict__ tb,
                                               float* __restrict__ gsum,
                                               float* __restrict__ gsumsq) {
    int b = blockIdx.y;
    int idx = blockIdx.x * 256 + threadIdx.x; // 0..65535
    int ch = idx & 63, pix = idx >> 6;
    size_t mrow = (size_t)b * 1024 + pix;
    float v = P4[mrow * 64 + ch] + P4[(4096 + mrow) * 64 + ch] +
              P4[(8192 + mrow) * 64 + ch] + P4[(12288 + mrow) * 64 + ch];
    v += bo[ch] + 2.f * qimg[((size_t)b * 64 + ch) * 1024 + pix];
    tb[((size_t)b * 64 + ch) * 1024 + pix] = v;
    float s = v, s2 = v * v;
#pragma unroll
    for (int o = 32; o; o >>= 1) { s += __shfl_xor(s, o); s2 += __shfl_xor(s2, o); }
    if ((threadIdx.x & 63) == 0) { atomicAdd(&gsum[b], s); atomicAdd(&gsumsq[b], s2); }
}

// ---------------- kernel 8: LayerNorm apply ----------------
__global__ __launch_bounds__(256) void k_post2(const float* __restrict__ tb,
                                               const float* __restrict__ gsum,
                                               const float* __restrict__ gsumsq,
                                               const float* __restrict__ lnw,
                                               const float* __restrict__ lnb,
                                               float* __restrict__ y) {
    int idx = blockIdx.x * 256 + threadIdx.x; // 262144
    int b = idx >> 16, rem = idx & 65535;
    float mean = gsum[b] * (1.f / 65536.f);
    float var = gsumsq[b] * (1.f / 65536.f) - mean * mean;
    float rstd = rsqrtf(var + 1e-6f);
    y[idx] = (tb[idx] - mean) * rstd * lnw[rem] + lnb[rem];
}

extern "C" void kernel_launch(void* const* d_in, const int* in_sizes, int n_in,
                              void* d_out, int out_size, void* d_ws, size_t ws_size,
                              hipStream_t stream) {
    const float* qimg = (const float*)d_in[0];
    const float* seq  = (const float*)d_in[1];
    const float* wq   = (const float*)d_in[2];
    const float* bq   = (const float*)d_in[3];
    const float* wk   = (const float*)d_in[4];
    const float* bk   = (const float*)d_in[5];
    const float* wv   = (const float*)d_in[6];
    const float* bv   = (const float*)d_in[7];
    const float* wo   = (const float*)d_in[8];
    const float* bo   = (const float*)d_in[9];
    const float* lnw  = (const float*)d_in[10];
    const float* lnb  = (const float*)d_in[11];
    float* out_y    = (float*)d_out;
    float* out_attn = out_y + 262144;

    size_t off = 0;
    auto alloc = [&](size_t bytes) {
        void* p = (char*)d_ws + off;
        off += (bytes + 255) & ~(size_t)255;
        return p;
    };
    u16*   wqb   = (u16*)alloc(147456 * 2);
    u16*   wkb   = (u16*)alloc(147456 * 2);
    u16*   wvb   = (u16*)alloc(147456 * 2);
    u16*   wob   = (u16*)alloc(147456 * 2);
    float* bqs   = (float*)alloc(256 * 4);
    u16*   imcol = (u16*)alloc((size_t)20480 * 576 * 2); // reused as xcol (4096*2304*2) later
    u16*   qb    = (u16*)alloc((size_t)4 * 8 * 1024 * 32 * 2);
    u16*   kb    = (u16*)alloc((size_t)4 * 8 * 4096 * 32 * 2);
    u16*   vb    = (u16*)alloc((size_t)4 * 8 * 4096 * 32 * 2);
    float* invZ  = (float*)alloc((size_t)4 * 8 * 4096 * 4);
    float* xb    = (float*)alloc((size_t)4 * 256 * 1024 * 4);
    float* P4    = (float*)alloc((size_t)4 * 4096 * 64 * 4);
    float* tb    = (float*)alloc((size_t)4 * 64 * 1024 * 4);
    float* gs    = (float*)alloc(32);

    hipMemsetAsync(gs, 0, 32, stream);
    k_wcast<<<576, 256, 0, stream>>>(wq, wk, wv, wo, bq, wqb, wkb, wvb, wob, bqs);
    k_imcol1<<<5120, 256, 0, stream>>>(qimg, seq, imcol);
    k_conv<<<dim3(32, 4, 1), 256, 0, stream>>>(imcol, 576, wqb, 576, bqs, 0, qb, (float*)nullptr);
    k_conv<<<dim3(128, 4, 1), 256, 0, stream>>>(imcol + (size_t)4096 * 576, 576, wkb, 576, bk, 1, kb, (float*)nullptr);
    k_conv<<<dim3(128, 4, 1), 256, 0, stream>>>(imcol + (size_t)4096 * 576, 576, wvb, 576, bv, 2, vb, (float*)nullptr);
    k_z<<<dim3(32, 16), 256, 0, stream>>>(qb, kb, invZ);
    k_attn<<<dim3(32, 16), 256, 0, stream>>>(qb, kb, vb, invZ, out_attn, xb);
    k_imcol2<<<4096, 256, 0, stream>>>(xb, imcol); // reuse imcol region as xcol
    k_conv<<<dim3(32, 1, 4), 256, 0, stream>>>(imcol, 2304, wob, 2304, (const float*)nullptr, 3, (u16*)nullptr, P4);
    k_post1<<<dim3(256, 4), 256, 0, stream>>>(P4, bo, qimg, tb, gs, gs + 4);
    k_post2<<<1024, 256, 0, stream>>>(tb, gs, gs + 4, lnw, lnb, out_y);
}